// Round 12
// baseline (346.767 us; speedup 1.0000x reference)
//
#include <hip/hip_runtime.h>
#include <hip/hip_bf16.h>

typedef unsigned short u16;

#define T_NODES 32768
#define NPG 1024
#define BGR 32
#define D 64
#define FIN 8

// ---- bf16 <-> f32 ----
__device__ __forceinline__ float bf2f(u16 u){ return __uint_as_float(((unsigned)u) << 16); }
__device__ __forceinline__ u16 f2bf(float f){
    __hip_bfloat16 h = __float2bfloat16(f);
    return *reinterpret_cast<u16*>(&h);
}
__device__ __forceinline__ float4 bf4(ushort4 u){
    return make_float4(bf2f(u.x), bf2f(u.y), bf2f(u.z), bf2f(u.w));
}
__device__ __forceinline__ ushort4 f2bf4(float4 v){
    ushort4 u; u.x=f2bf(v.x); u.y=f2bf(v.y); u.z=f2bf(v.z); u.w=f2bf(v.w); return u;
}

// ---- DPP add helpers (VALU pipe, no LDS traffic) ----
template<int CTRL, int RM, int BM>
__device__ __forceinline__ float dpp_add(float x){
    int y = __builtin_amdgcn_update_dpp(0, __float_as_int(x), CTRL, RM, BM, false);
    return x + __int_as_float(y);
}
__device__ __forceinline__ float wave_sum63(float x){
    x = dpp_add<0x111,0xf,0xf>(x);
    x = dpp_add<0x112,0xf,0xf>(x);
    x = dpp_add<0x114,0xf,0xe>(x);
    x = dpp_add<0x118,0xf,0xc>(x);
    x = dpp_add<0x142,0xa,0xf>(x);
    x = dpp_add<0x143,0xc,0xf>(x);
    return x;
}
__device__ __forceinline__ float wave_sum_bcast(float x){
    return __int_as_float(__builtin_amdgcn_readlane(__float_as_int(wave_sum63(x)), 63));
}
// 16-lane-row sum via rotate-add: every lane of the row ends with the row total
__device__ __forceinline__ float row_ror_add(float x){
    x = dpp_add<0x121,0xf,0xf>(x);
    x = dpp_add<0x122,0xf,0xf>(x);
    x = dpp_add<0x124,0xf,0xf>(x);
    x = dpp_add<0x128,0xf,0xf>(x);
    return x;
}

// ---- degree-tiered edge accumulation (NIT*4 edge slots, burst loads) ----
template<int NIT>
__device__ __forceinline__ void edge_fast(const u16* __restrict__ xlin,
        int sAll, int nEdge, int row, int sub4,
        float4 a4, float4 xr4, float4& acc, float& l){
    ushort4 u[NIT];
    #pragma unroll
    for (int i = 0; i < NIT; i++){
        int j = i*4 + row;
        int jc = (j < nEdge) ? j : (nEdge-1);
        int s = __shfl(sAll, jc, 64);
        u[i] = *(const ushort4*)&xlin[((size_t)(unsigned)s << 6) + sub4];
    }
    #pragma unroll
    for (int i = 0; i < NIT; i++){
        float4 xv = bf4(u[i]);
        float v, e;
        v = xv.x + xr4.x; v = fmaxf(v, 0.2f*v); e = v*a4.x;
        v = xv.y + xr4.y; v = fmaxf(v, 0.2f*v); e = fmaf(v, a4.y, e);
        v = xv.z + xr4.z; v = fmaxf(v, 0.2f*v); e = fmaf(v, a4.z, e);
        v = xv.w + xr4.w; v = fmaxf(v, 0.2f*v); e = fmaf(v, a4.w, e);
        e = row_ror_add(e);
        float q = (i*4 + row < nEdge) ? __expf(e) : 0.f;
        l += q;
        acc.x = fmaf(q, xv.x, acc.x);
        acc.y = fmaf(q, xv.y, acc.y);
        acc.z = fmaf(q, xv.z, acc.z);
        acc.w = fmaf(q, xv.w, acc.w);
    }
}

__device__ __forceinline__ void edge_slow(const u16* __restrict__ xlin,
        const int* __restrict__ col, int beg, int deg, int t,
        int sAll, int nEdge, int row, int sub4,
        float4 a4, float4 xr4, float4& acc, float& l){
    for (int j0 = 0; j0 < nEdge; j0 += 4){
        int j = j0 + row;
        int jc = (j < nEdge) ? j : (nEdge-1);
        int s;
        if (jc < 64) s = __shfl(sAll, jc, 64);
        else         s = (jc < deg) ? col[beg + jc] : t;
        float4 xv = bf4(*(const ushort4*)&xlin[((size_t)(unsigned)s << 6) + sub4]);
        float v, e;
        v = xv.x + xr4.x; v = fmaxf(v, 0.2f*v); e = v*a4.x;
        v = xv.y + xr4.y; v = fmaxf(v, 0.2f*v); e = fmaf(v, a4.y, e);
        v = xv.z + xr4.z; v = fmaxf(v, 0.2f*v); e = fmaf(v, a4.z, e);
        v = xv.w + xr4.w; v = fmaxf(v, 0.2f*v); e = fmaf(v, a4.w, e);
        e = row_ror_add(e);
        float q = (j < nEdge) ? __expf(e) : 0.f;
        l += q;
        acc.x = fmaf(q, xv.x, acc.x);
        acc.y = fmaf(q, xv.y, acc.y);
        acc.z = fmaf(q, xv.z, acc.z);
        acc.w = fmaf(q, xv.w, acc.w);
    }
}

// ---------------- CSR build ----------------
__global__ void count_kernel(const int* __restrict__ dst, int* __restrict__ counts, int E){
    int i = blockIdx.x*blockDim.x + threadIdx.x;
    if (i < E) atomicAdd(&counts[dst[i]], 1);
}

__global__ void scan_kernel(const int* __restrict__ counts, int* __restrict__ indptr,
                            int* __restrict__ cursor, int T){
    __shared__ int bufA[1024];
    __shared__ int bufB[1024];
    int tid = threadIdx.x;
    int base = tid * 32;
    int local[32];
    int s = 0;
    #pragma unroll
    for (int i = 0; i < 32; i++){ local[i] = counts[base+i]; s += local[i]; }
    bufA[tid] = s;
    __syncthreads();
    int* src = bufA; int* dst = bufB;
    for (int off = 1; off < 1024; off <<= 1){
        int v = src[tid];
        if (tid >= off) v += src[tid - off];
        dst[tid] = v;
        __syncthreads();
        int* t = src; src = dst; dst = t;
    }
    int excl = src[tid] - s;
    int run = excl;
    #pragma unroll
    for (int i = 0; i < 32; i++){
        indptr[base+i] = run;
        cursor[base+i] = run;
        run += local[i];
    }
    if (tid == 1023) indptr[T] = run;
}

__global__ void scatter_kernel(const int* __restrict__ src, const int* __restrict__ dst,
                               int* __restrict__ cursor, int* __restrict__ col, int E){
    int i = blockIdx.x*blockDim.x + threadIdx.x;
    if (i < E){
        int d = dst[i];
        int pos = atomicAdd(&cursor[d], 1);
        col[pos] = src[i];
    }
}

// ---------------- layer 0 linear + zero-init fused: bf16 xl/xr out ----------------
__global__ void lin0_kernel(const float* __restrict__ x, const float* __restrict__ Wl0,
                            const float* __restrict__ Wr0,
                            u16* __restrict__ xlb, u16* __restrict__ xrb,
                            int* __restrict__ counts, float* __restrict__ muAcc){
    __shared__ float wl[D][FIN+1];
    __shared__ float wr[D][FIN+1];
    __shared__ float xs[32][FIN];
    int tid = threadIdx.x;
    int blk = blockIdx.x;
    int gidx = blk*256 + tid;
    if (gidx < T_NODES) counts[gidx] = 0;             // fused zero
    if (gidx < BGR*D)   muAcc[gidx] = 0.f;
    int rowBase = (blk & 7)*4096 + (blk >> 3)*32;     // XCD swizzle
    for (int i = tid; i < D*FIN; i += 256){
        wl[i>>3][i&7] = Wl0[i];
        wr[i>>3][i&7] = Wr0[i];
    }
    xs[tid>>3][tid&7] = x[rowBase*FIN + tid];
    __syncthreads();
    int wave = tid >> 6, lane = tid & 63;
    int rb = rowBase + wave*8;
    #pragma unroll
    for (int r = 0; r < 8; r++){
        float al = 0.f, ar = 0.f;
        int lr = wave*8 + r;
        #pragma unroll
        for (int k = 0; k < FIN; k++){
            float xv = xs[lr][k];
            al = fmaf(xv, wl[lane][k], al);
            ar = fmaf(xv, wr[lane][k], ar);
        }
        xlb[(size_t)(rb+r)*D + lane] = f2bf(al);
        xrb[(size_t)(rb+r)*D + lane] = f2bf(ar);
    }
}

// ---------------- fused edge+lin, 16 nodes/block (grid 2048 -> 8 blk/CU) ----------
// Upfront prefetch: indptr (wave-uniform s_load), 4 col reads, 4 xr reads issued
// back-to-back before the node loop -> per-node critical path = gather only.
// LDS: bf16 weights 17.4 KB + bf16 h-stage 2.2 KB ~= 19.6 KB -> 8 blocks/CU.
__global__ __launch_bounds__(256) void el_kernel(
        const u16* __restrict__ xlin, const u16* __restrict__ xrin,
        const float* __restrict__ att, const float* __restrict__ bias,
        const int* __restrict__ indptr, const int* __restrict__ col,
        const float* __restrict__ Wl, const float* __restrict__ Wr,
        u16* __restrict__ xlout, u16* __restrict__ xrout, int E){
    __shared__ __align__(16) u16 hsb[16][68];
    __shared__ __align__(16) u16 wls[D][68];
    __shared__ __align__(16) u16 wrs[D][68];
    int tid = threadIdx.x, blk = blockIdx.x;
    int rowBase = (blk & 7)*4096 + (blk >> 3)*16;     // XCD swizzle
    for (int i = tid; i < D*D; i += 256){             // stage weights (bf16 in LDS)
        wls[i>>6][i&63] = f2bf(Wl[i]);
        wrs[i>>6][i&63] = f2bf(Wr[i]);
    }
    int wave = tid >> 6, lane = tid & 63;
    int row = lane >> 4, sub4 = (lane & 15) << 2;
    float4 a4 = *(const float4*)&att[sub4];
    float4 b4 = *(const float4*)&bias[sub4];
    int t0 = rowBase + wave*4;                        // this wave's 4 nodes
    // upfront: 5 wave-uniform indptr loads (s_load), then 4 col + 4 xr vector loads
    int ip[5];
    #pragma unroll
    for (int n = 0; n < 5; n++) ip[n] = indptr[t0 + n];
    int sAllv[4];
    ushort4 urv[4];
    #pragma unroll
    for (int n = 0; n < 4; n++){
        int beg = ip[n];
        int idx = beg + lane; idx = idx < E ? idx : E - 1;
        sAllv[n] = col[idx];
        urv[n] = *(const ushort4*)&xrin[((size_t)(t0+n) << 6) + sub4];
    }
    #pragma unroll
    for (int n = 0; n < 4; n++){
        int t = t0 + n;
        float4 xr4 = bf4(urv[n]);
        int deg = ip[n+1] - ip[n];
        int sAll = (lane < deg) ? sAllv[n] : t;
        int nEdge = deg + 1;
        float4 acc = make_float4(0.f,0.f,0.f,0.f);
        float l = 0.f;
        if      (nEdge <= 16) edge_fast<4>(xlin, sAll, nEdge, row, sub4, a4, xr4, acc, l);
        else if (nEdge <= 24) edge_fast<6>(xlin, sAll, nEdge, row, sub4, a4, xr4, acc, l);
        else if (nEdge <= 32) edge_fast<8>(xlin, sAll, nEdge, row, sub4, a4, xr4, acc, l);
        else edge_slow(xlin, col, ip[n], deg, t, sAll, nEdge, row, sub4, a4, xr4, acc, l);
        #pragma unroll
        for (int o = 16; o < 64; o <<= 1){
            acc.x += __shfl_xor(acc.x, o, 64);
            acc.y += __shfl_xor(acc.y, o, 64);
            acc.z += __shfl_xor(acc.z, o, 64);
            acc.w += __shfl_xor(acc.w, o, 64);
            l     += __shfl_xor(l,     o, 64);
        }
        if (row == 0){
            float4 hv;
            hv.x = fmaxf(acc.x / l + b4.x, 0.f);      // relu (input to lin)
            hv.y = fmaxf(acc.y / l + b4.y, 0.f);
            hv.z = fmaxf(acc.z / l + b4.z, 0.f);
            hv.w = fmaxf(acc.w / l + b4.w, 0.f);
            *(ushort4*)&hsb[wave*4 + n][sub4] = f2bf4(hv);
        }
    }
    __syncthreads();
    // ---- lin phase: 16x64 tile, each thread 1 row x 4 cols x {Wl,Wr} ----
    int ty = tid >> 4, tx = tid & 15;
    float accl[4], accr[4];
    #pragma unroll
    for (int j = 0; j < 4; j++){ accl[j] = 0.f; accr[j] = 0.f; }
    for (int k = 0; k < D; k += 4){
        float4 hv = bf4(*(const ushort4*)&hsb[ty][k]);
        #pragma unroll
        for (int j = 0; j < 4; j++){
            float4 wlv = bf4(*(const ushort4*)&wls[tx + 16*j][k]);
            float4 wrv = bf4(*(const ushort4*)&wrs[tx + 16*j][k]);
            accl[j] += hv.x*wlv.x + hv.y*wlv.y + hv.z*wlv.z + hv.w*wlv.w;
            accr[j] += hv.x*wrv.x + hv.y*wrv.y + hv.z*wrv.z + hv.w*wrv.w;
        }
    }
    size_t rowOff = (size_t)(rowBase + ty) * D;
    #pragma unroll
    for (int j = 0; j < 4; j++){
        xlout[rowOff + tx + 16*j] = f2bf(accl[j]);
        xrout[rowOff + tx + 16*j] = f2bf(accr[j]);
    }
}

// ---------------- last edge layer: bf16 in, fp32 h out + graph-mean ----------------
__global__ __launch_bounds__(256) void e4_kernel(
        const u16* __restrict__ xlin, const u16* __restrict__ xrin,
        const float* __restrict__ att, const float* __restrict__ bias,
        const int* __restrict__ indptr, const int* __restrict__ col,
        float* __restrict__ hout, float* __restrict__ muAcc, int E){
    int wave = threadIdx.x >> 6, lane = threadIdx.x & 63;
    int blk = blockIdx.x;
    int t = (blk & 7)*4096 + (blk >> 3)*4 + wave;
    int row = lane >> 4, sub4 = (lane & 15) << 2;
    float4 a4 = *(const float4*)&att[sub4];
    float4 xr4 = bf4(*(const ushort4*)&xrin[((size_t)t << 6) + sub4]);
    int beg = indptr[t], end = indptr[t+1];
    int deg = end - beg;
    int idx = beg + lane; idx = idx < E ? idx : E - 1;
    int sAll = (lane < deg) ? col[idx] : t;
    int nEdge = deg + 1;
    float4 acc = make_float4(0.f,0.f,0.f,0.f);
    float l = 0.f;
    if      (nEdge <= 16) edge_fast<4>(xlin, sAll, nEdge, row, sub4, a4, xr4, acc, l);
    else if (nEdge <= 24) edge_fast<6>(xlin, sAll, nEdge, row, sub4, a4, xr4, acc, l);
    else if (nEdge <= 32) edge_fast<8>(xlin, sAll, nEdge, row, sub4, a4, xr4, acc, l);
    else edge_slow(xlin, col, beg, deg, t, sAll, nEdge, row, sub4, a4, xr4, acc, l);
    #pragma unroll
    for (int o = 16; o < 64; o <<= 1){
        acc.x += __shfl_xor(acc.x, o, 64);
        acc.y += __shfl_xor(acc.y, o, 64);
        acc.z += __shfl_xor(acc.z, o, 64);
        acc.w += __shfl_xor(acc.w, o, 64);
        l     += __shfl_xor(l,     o, 64);
    }
    float4 b4 = *(const float4*)&bias[sub4];
    float4 hv;
    hv.x = acc.x / l + b4.x;                          // NO relu (final h)
    hv.y = acc.y / l + b4.y;
    hv.z = acc.z / l + b4.z;
    hv.w = acc.w / l + b4.w;
    if (row == 0)
        *(float4*)&hout[(size_t)t*D + sub4] = hv;
    __shared__ float red[4][D];
    if (row == 0) *(float4*)&red[wave][sub4] = hv;
    __syncthreads();
    if (wave == 0){
        float s = red[0][lane] + red[1][lane] + red[2][lane] + red[3][lane];
        atomicAdd(&muAcc[(t >> 10)*D + lane], s);
    }
}

// ---------------- per-node head with inlined per-graph pool ----------------
__global__ __launch_bounds__(256) void final_kernel(const float* __restrict__ h,
                             const float* __restrict__ muAcc,
                             const float* __restrict__ t6w, const float* __restrict__ t6b,
                             const float* __restrict__ t7w, const float* __restrict__ t7b,
                             const float* __restrict__ t5pw, const float* __restrict__ t5pb,
                             const float* __restrict__ t5vw, const float* __restrict__ t5vb,
                             const float* __restrict__ pw, const float* __restrict__ pb,
                             const int* __restrict__ reachable,
                             float* __restrict__ out_logits, float* __restrict__ qbuf){
    __shared__ __align__(16) float hs[D][68];
    __shared__ __align__(16) float ws[D][68];
    __shared__ float ppar[D][17];
    __shared__ float qpar[D][17];
    __shared__ float PgQg[2];
    int tid = threadIdx.x;
    int blk = blockIdx.x;
    int rowBase = (blk & 7)*4096 + (blk >> 3)*64;
    int b = rowBase >> 10;
    for (int i = tid; i < D*D; i += 256) ws[i>>6][i&63] = t6w[i];
    if (tid < D) hs[0][tid] = muAcc[b*D + tid] * (1.f/NPG);
    __syncthreads();
    if (tid < D){
        int d = tid;
        float g = t6b[d];
        #pragma unroll
        for (int k = 0; k < D; k++) g = fmaf(hs[0][k], ws[d][k], g);
        g = fmaxf(g, 0.f);
        float pp = wave_sum_bcast(g * t5pw[d]);
        float qq = wave_sum_bcast(g * t5vw[d]);
        if (d == 0){ PgQg[0] = pp; PgQg[1] = qq; }
    }
    __syncthreads();
    for (int i = tid; i < D*D; i += 256){
        int r = i >> 6, c = i & 63;
        hs[r][c] = h[(size_t)rowBase*D + i];
        ws[r][c] = t7w[i];
    }
    __syncthreads();
    int ty = tid >> 4, tx = tid & 15;
    int r0 = ty * 4;
    float acc[4][4];
    #pragma unroll
    for (int i = 0; i < 4; i++)
        #pragma unroll
        for (int j = 0; j < 4; j++) acc[i][j] = 0.f;
    for (int k = 0; k < D; k += 4){
        float4 hv[4], wv[4];
        #pragma unroll
        for (int i = 0; i < 4; i++){
            hv[i] = *(const float4*)&hs[r0+i][k];
            wv[i] = *(const float4*)&ws[tx + 16*i][k];
        }
        #pragma unroll
        for (int i = 0; i < 4; i++)
            #pragma unroll
            for (int j = 0; j < 4; j++)
                acc[i][j] += hv[i].x*wv[j].x + hv[i].y*wv[j].y
                           + hv[i].z*wv[j].z + hv[i].w*wv[j].w;
    }
    float bc[4], pwc[4], qwc[4];
    #pragma unroll
    for (int j = 0; j < 4; j++){
        int c = tx + 16*j;
        bc[j]  = t7b[c];
        pwc[j] = t5pw[D + c];
        qwc[j] = t5vw[D + c];
    }
    #pragma unroll
    for (int i = 0; i < 4; i++){
        float sp = 0.f, sq = 0.f;
        #pragma unroll
        for (int j = 0; j < 4; j++){
            float lv = fmaxf(acc[i][j] + bc[j], 0.f);
            sp = fmaf(lv, pwc[j], sp);
            sq = fmaf(lv, qwc[j], sq);
        }
        ppar[r0+i][tx] = sp;
        qpar[r0+i][tx] = sq;
    }
    __syncthreads();
    if (tid < 64){
        int t = rowBase + tid;
        float sp = 0.f, sq = 0.f;
        #pragma unroll
        for (int c = 0; c < 16; c++){ sp += ppar[tid][c]; sq += qpar[tid][c]; }
        float prob = PgQg[0] + sp + t5pb[0];
        out_logits[t] = prob * pw[0] + pb[0];
        float q = PgQg[1] + sq + t5vb[0];
        if (!reachable[t]) q = -1e20f;
        qbuf[t] = q;
    }
}

// ---------------- per-graph masked max -> value ----------------
__global__ void value_kernel(const float* __restrict__ qbuf, const float* __restrict__ vw,
                             const float* __restrict__ vb, float* __restrict__ out_value){
    __shared__ float part[256];
    int b = blockIdx.x, tid = threadIdx.x;
    float m = -INFINITY;
    for (int i = tid; i < NPG; i += 256) m = fmaxf(m, qbuf[b*NPG + i]);
    part[tid] = m;
    __syncthreads();
    for (int s = 128; s > 0; s >>= 1){
        if (tid < s) part[tid] = fmaxf(part[tid], part[tid+s]);
        __syncthreads();
    }
    if (tid == 0) out_value[b] = part[0]*vw[0] + vb[0];
}

extern "C" void kernel_launch(void* const* d_in, const int* in_sizes, int n_in,
                              void* d_out, int out_size, void* d_ws, size_t ws_size,
                              hipStream_t stream){
    const float* x          = (const float*)d_in[0];
    const int*   edge_index = (const int*)d_in[1];
    const int*   reachable  = (const int*)d_in[2];
    const float* Wl0 = (const float*)d_in[3];
    const float* Wr0 = (const float*)d_in[4];
    const float* att0= (const float*)d_in[5];
    const float* b0  = (const float*)d_in[6];
    const float* Wl  = (const float*)d_in[7];
    const float* Wr  = (const float*)d_in[8];
    const float* att = (const float*)d_in[9];
    const float* bb  = (const float*)d_in[10];
    const float* t6w = (const float*)d_in[11];
    const float* t6b = (const float*)d_in[12];
    const float* t7w = (const float*)d_in[13];
    const float* t7b = (const float*)d_in[14];
    const float* t5pw= (const float*)d_in[15];
    const float* t5pb= (const float*)d_in[16];
    const float* t5vw= (const float*)d_in[17];
    const float* t5vb= (const float*)d_in[18];
    const float* pw  = (const float*)d_in[19];
    const float* pb  = (const float*)d_in[20];
    const float* vw  = (const float*)d_in[21];
    const float* vb  = (const float*)d_in[22];

    int E = in_sizes[1] / 2;
    const int* esrc = edge_index;
    const int* edst = edge_index + E;

    char* ws = (char*)d_ws;
    float* h    = (float*)(ws);
    u16* xlbA   = (u16*)(ws + (size_t)T_NODES*D*4);
    u16* xrbA   = (u16*)((char*)xlbA + (size_t)T_NODES*D*2);
    u16* xlbB   = (u16*)((char*)xrbA + (size_t)T_NODES*D*2);
    u16* xrbB   = (u16*)((char*)xlbB + (size_t)T_NODES*D*2);
    int* counts = (int*)((char*)xrbB + (size_t)T_NODES*D*2);
    int* indptr = (int*)((char*)counts + (size_t)(T_NODES+16)*4);
    int* cursor = (int*)((char*)indptr + (size_t)(T_NODES+16)*4);
    int* col    = (int*)((char*)cursor + (size_t)(T_NODES+16)*4);
    float* qbuf = (float*)((char*)col + (size_t)(E+64)*4);
    float* muAcc= (float*)((char*)qbuf + (size_t)T_NODES*4);

    lin0_kernel<<<T_NODES/32, 256, 0, stream>>>(x, Wl0, Wr0, xlbA, xrbA, counts, muAcc);
    count_kernel<<<(E+255)/256, 256, 0, stream>>>(edst, counts, E);
    scan_kernel<<<1, 1024, 0, stream>>>(counts, indptr, cursor, T_NODES);
    scatter_kernel<<<(E+255)/256, 256, 0, stream>>>(esrc, edst, cursor, col, E);

    // EL_i: edge of layer i (+relu) then lin with Wl[i]/Wr[i]; ping-pong A/B
    el_kernel<<<T_NODES/16, 256, 0, stream>>>(xlbA, xrbA, att0, b0, indptr, col,
                                              Wl + 0*D*D, Wr + 0*D*D, xlbB, xrbB, E);
    el_kernel<<<T_NODES/16, 256, 0, stream>>>(xlbB, xrbB, att + 0*D, bb + 0*D, indptr, col,
                                              Wl + 1*D*D, Wr + 1*D*D, xlbA, xrbA, E);
    el_kernel<<<T_NODES/16, 256, 0, stream>>>(xlbA, xrbA, att + 1*D, bb + 1*D, indptr, col,
                                              Wl + 2*D*D, Wr + 2*D*D, xlbB, xrbB, E);
    el_kernel<<<T_NODES/16, 256, 0, stream>>>(xlbB, xrbB, att + 2*D, bb + 2*D, indptr, col,
                                              Wl + 3*D*D, Wr + 3*D*D, xlbA, xrbA, E);
    e4_kernel<<<T_NODES/4, 256, 0, stream>>>(xlbA, xrbA, att + 3*D, bb + 3*D, indptr, col,
                                             h, muAcc, E);

    final_kernel<<<T_NODES/64, 256, 0, stream>>>(h, muAcc, t6w, t6b, t7w, t7b,
                                                 t5pw, t5pb, t5vw, t5vb, pw, pb,
                                                 reachable, (float*)d_out, qbuf);
    value_kernel<<<BGR, 256, 0, stream>>>(qbuf, vw, vb, (float*)d_out + T_NODES);
}

// Round 13
// 324.240 us; speedup vs baseline: 1.0695x; 1.0695x over previous
//
#include <hip/hip_runtime.h>
#include <hip/hip_bf16.h>

typedef unsigned short u16;

#define T_NODES 32768
#define NPG 1024
#define BGR 32
#define D 64
#define FIN 8

// ---- bf16 <-> f32 ----
__device__ __forceinline__ float bf2f(u16 u){ return __uint_as_float(((unsigned)u) << 16); }
__device__ __forceinline__ u16 f2bf(float f){
    __hip_bfloat16 h = __float2bfloat16(f);
    return *reinterpret_cast<u16*>(&h);
}
__device__ __forceinline__ float4 bf4(ushort4 u){
    return make_float4(bf2f(u.x), bf2f(u.y), bf2f(u.z), bf2f(u.w));
}

// ---- DPP add helpers (VALU pipe, no LDS traffic) ----
template<int CTRL, int RM, int BM>
__device__ __forceinline__ float dpp_add(float x){
    int y = __builtin_amdgcn_update_dpp(0, __float_as_int(x), CTRL, RM, BM, false);
    return x + __int_as_float(y);
}
__device__ __forceinline__ float wave_sum63(float x){
    x = dpp_add<0x111,0xf,0xf>(x);
    x = dpp_add<0x112,0xf,0xf>(x);
    x = dpp_add<0x114,0xf,0xe>(x);
    x = dpp_add<0x118,0xf,0xc>(x);
    x = dpp_add<0x142,0xa,0xf>(x);
    x = dpp_add<0x143,0xc,0xf>(x);
    return x;
}
__device__ __forceinline__ float wave_sum_bcast(float x){
    return __int_as_float(__builtin_amdgcn_readlane(__float_as_int(wave_sum63(x)), 63));
}
// 16-lane-row sum via rotate-add: every lane of the row ends with the row total
__device__ __forceinline__ float row_ror_add(float x){
    x = dpp_add<0x121,0xf,0xf>(x);
    x = dpp_add<0x122,0xf,0xf>(x);
    x = dpp_add<0x124,0xf,0xf>(x);
    x = dpp_add<0x128,0xf,0xf>(x);
    return x;
}

// ---- degree-tiered edge accumulation (NIT*4 edge slots, burst loads) ----
template<int NIT>
__device__ __forceinline__ void edge_fast(const u16* __restrict__ xlin,
        int sAll, int nEdge, int row, int sub4,
        float4 a4, float4 xr4, float4& acc, float& l){
    ushort4 u[NIT];
    #pragma unroll
    for (int i = 0; i < NIT; i++){
        int j = i*4 + row;
        int jc = (j < nEdge) ? j : (nEdge-1);
        int s = __shfl(sAll, jc, 64);
        u[i] = *(const ushort4*)&xlin[((size_t)(unsigned)s << 6) + sub4];
    }
    #pragma unroll
    for (int i = 0; i < NIT; i++){
        float4 xv = bf4(u[i]);
        float v, e;
        v = xv.x + xr4.x; v = fmaxf(v, 0.2f*v); e = v*a4.x;
        v = xv.y + xr4.y; v = fmaxf(v, 0.2f*v); e = fmaf(v, a4.y, e);
        v = xv.z + xr4.z; v = fmaxf(v, 0.2f*v); e = fmaf(v, a4.z, e);
        v = xv.w + xr4.w; v = fmaxf(v, 0.2f*v); e = fmaf(v, a4.w, e);
        e = row_ror_add(e);
        float q = (i*4 + row < nEdge) ? __expf(e) : 0.f;
        l += q;
        acc.x = fmaf(q, xv.x, acc.x);
        acc.y = fmaf(q, xv.y, acc.y);
        acc.z = fmaf(q, xv.z, acc.z);
        acc.w = fmaf(q, xv.w, acc.w);
    }
}

__device__ __forceinline__ void edge_slow(const u16* __restrict__ xlin,
        const int* __restrict__ col, int beg, int deg, int t,
        int sAll, int nEdge, int row, int sub4,
        float4 a4, float4 xr4, float4& acc, float& l){
    for (int j0 = 0; j0 < nEdge; j0 += 4){
        int j = j0 + row;
        int jc = (j < nEdge) ? j : (nEdge-1);
        int s;
        if (jc < 64) s = __shfl(sAll, jc, 64);
        else         s = (jc < deg) ? col[beg + jc] : t;
        float4 xv = bf4(*(const ushort4*)&xlin[((size_t)(unsigned)s << 6) + sub4]);
        float v, e;
        v = xv.x + xr4.x; v = fmaxf(v, 0.2f*v); e = v*a4.x;
        v = xv.y + xr4.y; v = fmaxf(v, 0.2f*v); e = fmaf(v, a4.y, e);
        v = xv.z + xr4.z; v = fmaxf(v, 0.2f*v); e = fmaf(v, a4.z, e);
        v = xv.w + xr4.w; v = fmaxf(v, 0.2f*v); e = fmaf(v, a4.w, e);
        e = row_ror_add(e);
        float q = (j < nEdge) ? __expf(e) : 0.f;
        l += q;
        acc.x = fmaf(q, xv.x, acc.x);
        acc.y = fmaf(q, xv.y, acc.y);
        acc.z = fmaf(q, xv.z, acc.z);
        acc.w = fmaf(q, xv.w, acc.w);
    }
}

// ---------------- CSR build ----------------
__global__ void count_kernel(const int* __restrict__ dst, int* __restrict__ counts, int E){
    int i = blockIdx.x*blockDim.x + threadIdx.x;
    if (i < E) atomicAdd(&counts[dst[i]], 1);
}

__global__ void scan_kernel(const int* __restrict__ counts, int* __restrict__ indptr,
                            int* __restrict__ cursor, int T){
    __shared__ int bufA[1024];
    __shared__ int bufB[1024];
    int tid = threadIdx.x;
    int base = tid * 32;
    int local[32];
    int s = 0;
    #pragma unroll
    for (int i = 0; i < 32; i++){ local[i] = counts[base+i]; s += local[i]; }
    bufA[tid] = s;
    __syncthreads();
    int* src = bufA; int* dst = bufB;
    for (int off = 1; off < 1024; off <<= 1){
        int v = src[tid];
        if (tid >= off) v += src[tid - off];
        dst[tid] = v;
        __syncthreads();
        int* t = src; src = dst; dst = t;
    }
    int excl = src[tid] - s;
    int run = excl;
    #pragma unroll
    for (int i = 0; i < 32; i++){
        indptr[base+i] = run;
        cursor[base+i] = run;
        run += local[i];
    }
    if (tid == 1023) indptr[T] = run;
}

__global__ void scatter_kernel(const int* __restrict__ src, const int* __restrict__ dst,
                               int* __restrict__ cursor, int* __restrict__ col, int E){
    int i = blockIdx.x*blockDim.x + threadIdx.x;
    if (i < E){
        int d = dst[i];
        int pos = atomicAdd(&cursor[d], 1);
        col[pos] = src[i];
    }
}

// ---------------- layer 0 linear + zero-init fused: bf16 xl/xr out ----------------
__global__ void lin0_kernel(const float* __restrict__ x, const float* __restrict__ Wl0,
                            const float* __restrict__ Wr0,
                            u16* __restrict__ xlb, u16* __restrict__ xrb,
                            int* __restrict__ counts, float* __restrict__ muAcc){
    __shared__ float wl[D][FIN+1];
    __shared__ float wr[D][FIN+1];
    __shared__ float xs[32][FIN];
    int tid = threadIdx.x;
    int blk = blockIdx.x;
    int gidx = blk*256 + tid;
    if (gidx < T_NODES) counts[gidx] = 0;             // fused zero
    if (gidx < BGR*D)   muAcc[gidx] = 0.f;
    int rowBase = (blk & 7)*4096 + (blk >> 3)*32;     // XCD swizzle
    for (int i = tid; i < D*FIN; i += 256){
        wl[i>>3][i&7] = Wl0[i];
        wr[i>>3][i&7] = Wr0[i];
    }
    xs[tid>>3][tid&7] = x[rowBase*FIN + tid];
    __syncthreads();
    int wave = tid >> 6, lane = tid & 63;
    int rb = rowBase + wave*8;
    #pragma unroll
    for (int r = 0; r < 8; r++){
        float al = 0.f, ar = 0.f;
        int lr = wave*8 + r;
        #pragma unroll
        for (int k = 0; k < FIN; k++){
            float xv = xs[lr][k];
            al = fmaf(xv, wl[lane][k], al);
            ar = fmaf(xv, wr[lane][k], ar);
        }
        xlb[(size_t)(rb+r)*D + lane] = f2bf(al);
        xrb[(size_t)(rb+r)*D + lane] = f2bf(ar);
    }
}

// ---------------- fused edge+lin, 32 nodes/block (R11 config, 313.9us) ----------
// + upfront dependency-chain hoist: 9 indptr (s_load) then 8 col + 8 xr loads
// issued back-to-back before the node loop -> 16 loads in flight.
__global__ __launch_bounds__(256) void el_kernel(
        const u16* __restrict__ xlin, const u16* __restrict__ xrin,
        const float* __restrict__ att, const float* __restrict__ bias,
        const int* __restrict__ indptr, const int* __restrict__ col,
        const float* __restrict__ Wl, const float* __restrict__ Wr,
        u16* __restrict__ xlout, u16* __restrict__ xrout, int E){
    __shared__ __align__(16) float hs[32][68];
    __shared__ __align__(16) u16 wls[D][68];
    __shared__ __align__(16) u16 wrs[D][68];
    int tid = threadIdx.x, blk = blockIdx.x;
    int rowBase = (blk & 7)*4096 + (blk >> 3)*32;     // XCD swizzle
    for (int i = tid; i < D*D; i += 256){             // stage weights (bf16 in LDS)
        wls[i>>6][i&63] = f2bf(Wl[i]);
        wrs[i>>6][i&63] = f2bf(Wr[i]);
    }
    int wave = tid >> 6, lane = tid & 63;
    int row = lane >> 4, sub4 = (lane & 15) << 2;
    float4 a4 = *(const float4*)&att[sub4];
    float4 b4 = *(const float4*)&bias[sub4];
    int t0 = rowBase + wave*8;                        // this wave's 8 nodes
    // ---- upfront prefetch: break the per-node serial chain ----
    int ip[9];
    #pragma unroll
    for (int n = 0; n < 9; n++) ip[n] = indptr[t0 + n];   // wave-uniform
    int sAllv[8];
    ushort4 urv[8];
    #pragma unroll
    for (int n = 0; n < 8; n++){
        int idx = ip[n] + lane; idx = idx < E ? idx : E - 1;
        sAllv[n] = col[idx];                               // 8 coalesced loads in flight
        urv[n] = *(const ushort4*)&xrin[((size_t)(t0+n) << 6) + sub4];
    }
    for (int n = 0; n < 8; n++){                      // 8 nodes per wave
        int t  = t0 + n;
        float4 xr4 = bf4(urv[n]);
        int deg = ip[n+1] - ip[n];
        int sAll = (lane < deg) ? sAllv[n] : t;
        int nEdge = deg + 1;
        float4 acc = make_float4(0.f,0.f,0.f,0.f);
        float l = 0.f;
        if      (nEdge <= 16) edge_fast<4>(xlin, sAll, nEdge, row, sub4, a4, xr4, acc, l);
        else if (nEdge <= 24) edge_fast<6>(xlin, sAll, nEdge, row, sub4, a4, xr4, acc, l);
        else if (nEdge <= 32) edge_fast<8>(xlin, sAll, nEdge, row, sub4, a4, xr4, acc, l);
        else edge_slow(xlin, col, ip[n], deg, t, sAll, nEdge, row, sub4, a4, xr4, acc, l);
        #pragma unroll
        for (int o = 16; o < 64; o <<= 1){
            acc.x += __shfl_xor(acc.x, o, 64);
            acc.y += __shfl_xor(acc.y, o, 64);
            acc.z += __shfl_xor(acc.z, o, 64);
            acc.w += __shfl_xor(acc.w, o, 64);
            l     += __shfl_xor(l,     o, 64);
        }
        if (row == 0){
            float4 hv;
            hv.x = fmaxf(acc.x / l + b4.x, 0.f);      // relu (input to lin)
            hv.y = fmaxf(acc.y / l + b4.y, 0.f);
            hv.z = fmaxf(acc.z / l + b4.z, 0.f);
            hv.w = fmaxf(acc.w / l + b4.w, 0.f);
            *(float4*)&hs[wave*8 + n][sub4] = hv;
        }
    }
    __syncthreads();
    // ---- lin phase: 32x64 tile, each thread 2 rows x 4 cols x {Wl,Wr} ----
    int ty = tid >> 4, tx = tid & 15;
    int r0 = ty * 2;
    float accl[2][4], accr[2][4];
    #pragma unroll
    for (int i = 0; i < 2; i++)
        #pragma unroll
        for (int j = 0; j < 4; j++){ accl[i][j] = 0.f; accr[i][j] = 0.f; }
    for (int k = 0; k < D; k += 4){
        float4 hv[2], wlv[4], wrv[4];
        #pragma unroll
        for (int i = 0; i < 2; i++)
            hv[i] = *(const float4*)&hs[r0+i][k];
        #pragma unroll
        for (int j = 0; j < 4; j++){
            wlv[j] = bf4(*(const ushort4*)&wls[tx + 16*j][k]);
            wrv[j] = bf4(*(const ushort4*)&wrs[tx + 16*j][k]);
        }
        #pragma unroll
        for (int i = 0; i < 2; i++){
            #pragma unroll
            for (int j = 0; j < 4; j++){
                accl[i][j] += hv[i].x*wlv[j].x + hv[i].y*wlv[j].y
                            + hv[i].z*wlv[j].z + hv[i].w*wlv[j].w;
                accr[i][j] += hv[i].x*wrv[j].x + hv[i].y*wrv[j].y
                            + hv[i].z*wrv[j].z + hv[i].w*wrv[j].w;
            }
        }
    }
    #pragma unroll
    for (int i = 0; i < 2; i++){
        size_t rowOff = (size_t)(rowBase + r0 + i) * D;
        #pragma unroll
        for (int j = 0; j < 4; j++){
            xlout[rowOff + tx + 16*j] = f2bf(accl[i][j]);
            xrout[rowOff + tx + 16*j] = f2bf(accr[i][j]);
        }
    }
}

// ---------------- last edge layer: bf16 in, fp32 h out + graph-mean ----------------
__global__ __launch_bounds__(256) void e4_kernel(
        const u16* __restrict__ xlin, const u16* __restrict__ xrin,
        const float* __restrict__ att, const float* __restrict__ bias,
        const int* __restrict__ indptr, const int* __restrict__ col,
        float* __restrict__ hout, float* __restrict__ muAcc, int E){
    int wave = threadIdx.x >> 6, lane = threadIdx.x & 63;
    int blk = blockIdx.x;
    int t = (blk & 7)*4096 + (blk >> 3)*4 + wave;
    int row = lane >> 4, sub4 = (lane & 15) << 2;
    float4 a4 = *(const float4*)&att[sub4];
    float4 xr4 = bf4(*(const ushort4*)&xrin[((size_t)t << 6) + sub4]);
    int beg = indptr[t], end = indptr[t+1];
    int deg = end - beg;
    int idx = beg + lane; idx = idx < E ? idx : E - 1;
    int sAll = (lane < deg) ? col[idx] : t;
    int nEdge = deg + 1;
    float4 acc = make_float4(0.f,0.f,0.f,0.f);
    float l = 0.f;
    if      (nEdge <= 16) edge_fast<4>(xlin, sAll, nEdge, row, sub4, a4, xr4, acc, l);
    else if (nEdge <= 24) edge_fast<6>(xlin, sAll, nEdge, row, sub4, a4, xr4, acc, l);
    else if (nEdge <= 32) edge_fast<8>(xlin, sAll, nEdge, row, sub4, a4, xr4, acc, l);
    else edge_slow(xlin, col, beg, deg, t, sAll, nEdge, row, sub4, a4, xr4, acc, l);
    #pragma unroll
    for (int o = 16; o < 64; o <<= 1){
        acc.x += __shfl_xor(acc.x, o, 64);
        acc.y += __shfl_xor(acc.y, o, 64);
        acc.z += __shfl_xor(acc.z, o, 64);
        acc.w += __shfl_xor(acc.w, o, 64);
        l     += __shfl_xor(l,     o, 64);
    }
    float4 b4 = *(const float4*)&bias[sub4];
    float4 hv;
    hv.x = acc.x / l + b4.x;                          // NO relu (final h)
    hv.y = acc.y / l + b4.y;
    hv.z = acc.z / l + b4.z;
    hv.w = acc.w / l + b4.w;
    if (row == 0)
        *(float4*)&hout[(size_t)t*D + sub4] = hv;
    __shared__ float red[4][D];
    if (row == 0) *(float4*)&red[wave][sub4] = hv;
    __syncthreads();
    if (wave == 0){
        float s = red[0][lane] + red[1][lane] + red[2][lane] + red[3][lane];
        atomicAdd(&muAcc[(t >> 10)*D + lane], s);
    }
}

// ---------------- per-node head with inlined per-graph pool ----------------
__global__ __launch_bounds__(256) void final_kernel(const float* __restrict__ h,
                             const float* __restrict__ muAcc,
                             const float* __restrict__ t6w, const float* __restrict__ t6b,
                             const float* __restrict__ t7w, const float* __restrict__ t7b,
                             const float* __restrict__ t5pw, const float* __restrict__ t5pb,
                             const float* __restrict__ t5vw, const float* __restrict__ t5vb,
                             const float* __restrict__ pw, const float* __restrict__ pb,
                             const int* __restrict__ reachable,
                             float* __restrict__ out_logits, float* __restrict__ qbuf){
    __shared__ __align__(16) float hs[D][68];
    __shared__ __align__(16) float ws[D][68];
    __shared__ float ppar[D][17];
    __shared__ float qpar[D][17];
    __shared__ float PgQg[2];
    int tid = threadIdx.x;
    int blk = blockIdx.x;
    int rowBase = (blk & 7)*4096 + (blk >> 3)*64;
    int b = rowBase >> 10;
    for (int i = tid; i < D*D; i += 256) ws[i>>6][i&63] = t6w[i];
    if (tid < D) hs[0][tid] = muAcc[b*D + tid] * (1.f/NPG);
    __syncthreads();
    if (tid < D){
        int d = tid;
        float g = t6b[d];
        #pragma unroll
        for (int k = 0; k < D; k++) g = fmaf(hs[0][k], ws[d][k], g);
        g = fmaxf(g, 0.f);
        float pp = wave_sum_bcast(g * t5pw[d]);
        float qq = wave_sum_bcast(g * t5vw[d]);
        if (d == 0){ PgQg[0] = pp; PgQg[1] = qq; }
    }
    __syncthreads();
    for (int i = tid; i < D*D; i += 256){
        int r = i >> 6, c = i & 63;
        hs[r][c] = h[(size_t)rowBase*D + i];
        ws[r][c] = t7w[i];
    }
    __syncthreads();
    int ty = tid >> 4, tx = tid & 15;
    int r0 = ty * 4;
    float acc[4][4];
    #pragma unroll
    for (int i = 0; i < 4; i++)
        #pragma unroll
        for (int j = 0; j < 4; j++) acc[i][j] = 0.f;
    for (int k = 0; k < D; k += 4){
        float4 hv[4], wv[4];
        #pragma unroll
        for (int i = 0; i < 4; i++){
            hv[i] = *(const float4*)&hs[r0+i][k];
            wv[i] = *(const float4*)&ws[tx + 16*i][k];
        }
        #pragma unroll
        for (int i = 0; i < 4; i++)
            #pragma unroll
            for (int j = 0; j < 4; j++)
                acc[i][j] += hv[i].x*wv[j].x + hv[i].y*wv[j].y
                           + hv[i].z*wv[j].z + hv[i].w*wv[j].w;
    }
    float bc[4], pwc[4], qwc[4];
    #pragma unroll
    for (int j = 0; j < 4; j++){
        int c = tx + 16*j;
        bc[j]  = t7b[c];
        pwc[j] = t5pw[D + c];
        qwc[j] = t5vw[D + c];
    }
    #pragma unroll
    for (int i = 0; i < 4; i++){
        float sp = 0.f, sq = 0.f;
        #pragma unroll
        for (int j = 0; j < 4; j++){
            float lv = fmaxf(acc[i][j] + bc[j], 0.f);
            sp = fmaf(lv, pwc[j], sp);
            sq = fmaf(lv, qwc[j], sq);
        }
        ppar[r0+i][tx] = sp;
        qpar[r0+i][tx] = sq;
    }
    __syncthreads();
    if (tid < 64){
        int t = rowBase + tid;
        float sp = 0.f, sq = 0.f;
        #pragma unroll
        for (int c = 0; c < 16; c++){ sp += ppar[tid][c]; sq += qpar[tid][c]; }
        float prob = PgQg[0] + sp + t5pb[0];
        out_logits[t] = prob * pw[0] + pb[0];
        float q = PgQg[1] + sq + t5vb[0];
        if (!reachable[t]) q = -1e20f;
        qbuf[t] = q;
    }
}

// ---------------- per-graph masked max -> value ----------------
__global__ void value_kernel(const float* __restrict__ qbuf, const float* __restrict__ vw,
                             const float* __restrict__ vb, float* __restrict__ out_value){
    __shared__ float part[256];
    int b = blockIdx.x, tid = threadIdx.x;
    float m = -INFINITY;
    for (int i = tid; i < NPG; i += 256) m = fmaxf(m, qbuf[b*NPG + i]);
    part[tid] = m;
    __syncthreads();
    for (int s = 128; s > 0; s >>= 1){
        if (tid < s) part[tid] = fmaxf(part[tid], part[tid+s]);
        __syncthreads();
    }
    if (tid == 0) out_value[b] = part[0]*vw[0] + vb[0];
}

extern "C" void kernel_launch(void* const* d_in, const int* in_sizes, int n_in,
                              void* d_out, int out_size, void* d_ws, size_t ws_size,
                              hipStream_t stream){
    const float* x          = (const float*)d_in[0];
    const int*   edge_index = (const int*)d_in[1];
    const int*   reachable  = (const int*)d_in[2];
    const float* Wl0 = (const float*)d_in[3];
    const float* Wr0 = (const float*)d_in[4];
    const float* att0= (const float*)d_in[5];
    const float* b0  = (const float*)d_in[6];
    const float* Wl  = (const float*)d_in[7];
    const float* Wr  = (const float*)d_in[8];
    const float* att = (const float*)d_in[9];
    const float* bb  = (const float*)d_in[10];
    const float* t6w = (const float*)d_in[11];
    const float* t6b = (const float*)d_in[12];
    const float* t7w = (const float*)d_in[13];
    const float* t7b = (const float*)d_in[14];
    const float* t5pw= (const float*)d_in[15];
    const float* t5pb= (const float*)d_in[16];
    const float* t5vw= (const float*)d_in[17];
    const float* t5vb= (const float*)d_in[18];
    const float* pw  = (const float*)d_in[19];
    const float* pb  = (const float*)d_in[20];
    const float* vw  = (const float*)d_in[21];
    const float* vb  = (const float*)d_in[22];

    int E = in_sizes[1] / 2;
    const int* esrc = edge_index;
    const int* edst = edge_index + E;

    char* ws = (char*)d_ws;
    float* h    = (float*)(ws);
    u16* xlbA   = (u16*)(ws + (size_t)T_NODES*D*4);
    u16* xrbA   = (u16*)((char*)xlbA + (size_t)T_NODES*D*2);
    u16* xlbB   = (u16*)((char*)xrbA + (size_t)T_NODES*D*2);
    u16* xrbB   = (u16*)((char*)xlbB + (size_t)T_NODES*D*2);
    int* counts = (int*)((char*)xrbB + (size_t)T_NODES*D*2);
    int* indptr = (int*)((char*)counts + (size_t)(T_NODES+16)*4);
    int* cursor = (int*)((char*)indptr + (size_t)(T_NODES+16)*4);
    int* col    = (int*)((char*)cursor + (size_t)(T_NODES+16)*4);
    float* qbuf = (float*)((char*)col + (size_t)(E+64)*4);
    float* muAcc= (float*)((char*)qbuf + (size_t)T_NODES*4);

    lin0_kernel<<<T_NODES/32, 256, 0, stream>>>(x, Wl0, Wr0, xlbA, xrbA, counts, muAcc);
    count_kernel<<<(E+255)/256, 256, 0, stream>>>(edst, counts, E);
    scan_kernel<<<1, 1024, 0, stream>>>(counts, indptr, cursor, T_NODES);
    scatter_kernel<<<(E+255)/256, 256, 0, stream>>>(esrc, edst, cursor, col, E);

    // EL_i: edge of layer i (+relu) then lin with Wl[i]/Wr[i]; ping-pong A/B
    el_kernel<<<T_NODES/32, 256, 0, stream>>>(xlbA, xrbA, att0, b0, indptr, col,
                                              Wl + 0*D*D, Wr + 0*D*D, xlbB, xrbB, E);
    el_kernel<<<T_NODES/32, 256, 0, stream>>>(xlbB, xrbB, att + 0*D, bb + 0*D, indptr, col,
                                              Wl + 1*D*D, Wr + 1*D*D, xlbA, xrbA, E);
    el_kernel<<<T_NODES/32, 256, 0, stream>>>(xlbA, xrbA, att + 1*D, bb + 1*D, indptr, col,
                                              Wl + 2*D*D, Wr + 2*D*D, xlbB, xrbB, E);
    el_kernel<<<T_NODES/32, 256, 0, stream>>>(xlbB, xrbB, att + 2*D, bb + 2*D, indptr, col,
                                              Wl + 3*D*D, Wr + 3*D*D, xlbA, xrbA, E);
    e4_kernel<<<T_NODES/4, 256, 0, stream>>>(xlbA, xrbA, att + 3*D, bb + 3*D, indptr, col,
                                             h, muAcc, E);

    final_kernel<<<T_NODES/64, 256, 0, stream>>>(h, muAcc, t6w, t6b, t7w, t7b,
                                                 t5pw, t5pb, t5vw, t5vb, pw, pb,
                                                 reachable, (float*)d_out, qbuf);
    value_kernel<<<BGR, 256, 0, stream>>>(qbuf, vw, vb, (float*)d_out + T_NODES);
}

// Round 14
// 317.075 us; speedup vs baseline: 1.0936x; 1.0226x over previous
//
#include <hip/hip_runtime.h>
#include <hip/hip_bf16.h>

typedef unsigned short u16;

#define T_NODES 32768
#define NPG 1024
#define BGR 32
#define D 64
#define FIN 8

// ---- bf16 <-> f32 ----
__device__ __forceinline__ float bf2f(u16 u){ return __uint_as_float(((unsigned)u) << 16); }
__device__ __forceinline__ u16 f2bf(float f){
    __hip_bfloat16 h = __float2bfloat16(f);
    return *reinterpret_cast<u16*>(&h);
}
__device__ __forceinline__ float4 bf4(ushort4 u){
    return make_float4(bf2f(u.x), bf2f(u.y), bf2f(u.z), bf2f(u.w));
}
__device__ __forceinline__ ushort4 f2bf4(float4 v){
    ushort4 u; u.x=f2bf(v.x); u.y=f2bf(v.y); u.z=f2bf(v.z); u.w=f2bf(v.w); return u;
}

// ---- DPP add helpers (VALU pipe, no LDS traffic) ----
template<int CTRL, int RM, int BM>
__device__ __forceinline__ float dpp_add(float x){
    int y = __builtin_amdgcn_update_dpp(0, __float_as_int(x), CTRL, RM, BM, false);
    return x + __int_as_float(y);
}
__device__ __forceinline__ float wave_sum63(float x){
    x = dpp_add<0x111,0xf,0xf>(x);
    x = dpp_add<0x112,0xf,0xf>(x);
    x = dpp_add<0x114,0xf,0xe>(x);
    x = dpp_add<0x118,0xf,0xc>(x);
    x = dpp_add<0x142,0xa,0xf>(x);
    x = dpp_add<0x143,0xc,0xf>(x);
    return x;
}
__device__ __forceinline__ float wave_sum_bcast(float x){
    return __int_as_float(__builtin_amdgcn_readlane(__float_as_int(wave_sum63(x)), 63));
}
// 16-lane-row sum via rotate-add: every lane of the row ends with the row total
__device__ __forceinline__ float row_ror_add(float x){
    x = dpp_add<0x121,0xf,0xf>(x);
    x = dpp_add<0x122,0xf,0xf>(x);
    x = dpp_add<0x124,0xf,0xf>(x);
    x = dpp_add<0x128,0xf,0xf>(x);
    return x;
}

// ---- degree-tiered edge accumulation (NIT*4 edge slots, burst loads) ----
template<int NIT>
__device__ __forceinline__ void edge_fast(const u16* __restrict__ xlin,
        int sAll, int nEdge, int row, int sub4,
        float4 a4, float4 xr4, float4& acc, float& l){
    ushort4 u[NIT];
    #pragma unroll
    for (int i = 0; i < NIT; i++){
        int j = i*4 + row;
        int jc = (j < nEdge) ? j : (nEdge-1);
        int s = __shfl(sAll, jc, 64);
        u[i] = *(const ushort4*)&xlin[((size_t)(unsigned)s << 6) + sub4];
    }
    #pragma unroll
    for (int i = 0; i < NIT; i++){
        float4 xv = bf4(u[i]);
        float v, e;
        v = xv.x + xr4.x; v = fmaxf(v, 0.2f*v); e = v*a4.x;
        v = xv.y + xr4.y; v = fmaxf(v, 0.2f*v); e = fmaf(v, a4.y, e);
        v = xv.z + xr4.z; v = fmaxf(v, 0.2f*v); e = fmaf(v, a4.z, e);
        v = xv.w + xr4.w; v = fmaxf(v, 0.2f*v); e = fmaf(v, a4.w, e);
        e = row_ror_add(e);
        float q = (i*4 + row < nEdge) ? __expf(e) : 0.f;
        l += q;
        acc.x = fmaf(q, xv.x, acc.x);
        acc.y = fmaf(q, xv.y, acc.y);
        acc.z = fmaf(q, xv.z, acc.z);
        acc.w = fmaf(q, xv.w, acc.w);
    }
}

__device__ __forceinline__ void edge_slow(const u16* __restrict__ xlin,
        const int* __restrict__ col, int beg, int deg, int t,
        int sAll, int nEdge, int row, int sub4,
        float4 a4, float4 xr4, float4& acc, float& l){
    for (int j0 = 0; j0 < nEdge; j0 += 4){
        int j = j0 + row;
        int jc = (j < nEdge) ? j : (nEdge-1);
        int s;
        if (jc < 64) s = __shfl(sAll, jc, 64);
        else         s = (jc < deg) ? col[beg + jc] : t;
        float4 xv = bf4(*(const ushort4*)&xlin[((size_t)(unsigned)s << 6) + sub4]);
        float v, e;
        v = xv.x + xr4.x; v = fmaxf(v, 0.2f*v); e = v*a4.x;
        v = xv.y + xr4.y; v = fmaxf(v, 0.2f*v); e = fmaf(v, a4.y, e);
        v = xv.z + xr4.z; v = fmaxf(v, 0.2f*v); e = fmaf(v, a4.z, e);
        v = xv.w + xr4.w; v = fmaxf(v, 0.2f*v); e = fmaf(v, a4.w, e);
        e = row_ror_add(e);
        float q = (j < nEdge) ? __expf(e) : 0.f;
        l += q;
        acc.x = fmaf(q, xv.x, acc.x);
        acc.y = fmaf(q, xv.y, acc.y);
        acc.z = fmaf(q, xv.z, acc.z);
        acc.w = fmaf(q, xv.w, acc.w);
    }
}

// ---------------- CSR build ----------------
__global__ void count_kernel(const int* __restrict__ dst, int* __restrict__ counts, int E){
    int i = blockIdx.x*blockDim.x + threadIdx.x;
    if (i < E) atomicAdd(&counts[dst[i]], 1);
}

__global__ void scan_kernel(const int* __restrict__ counts, int* __restrict__ indptr,
                            int* __restrict__ cursor, int T){
    __shared__ int bufA[1024];
    __shared__ int bufB[1024];
    int tid = threadIdx.x;
    int base = tid * 32;
    int local[32];
    int s = 0;
    #pragma unroll
    for (int i = 0; i < 32; i++){ local[i] = counts[base+i]; s += local[i]; }
    bufA[tid] = s;
    __syncthreads();
    int* src = bufA; int* dst = bufB;
    for (int off = 1; off < 1024; off <<= 1){
        int v = src[tid];
        if (tid >= off) v += src[tid - off];
        dst[tid] = v;
        __syncthreads();
        int* t = src; src = dst; dst = t;
    }
    int excl = src[tid] - s;
    int run = excl;
    #pragma unroll
    for (int i = 0; i < 32; i++){
        indptr[base+i] = run;
        cursor[base+i] = run;
        run += local[i];
    }
    if (tid == 1023) indptr[T] = run;
}

__global__ void scatter_kernel(const int* __restrict__ src, const int* __restrict__ dst,
                               int* __restrict__ cursor, int* __restrict__ col, int E){
    int i = blockIdx.x*blockDim.x + threadIdx.x;
    if (i < E){
        int d = dst[i];
        int pos = atomicAdd(&cursor[d], 1);
        col[pos] = src[i];
    }
}

// ---------------- layer 0 linear + zero-init fused: bf16 xl/xr out ----------------
__global__ void lin0_kernel(const float* __restrict__ x, const float* __restrict__ Wl0,
                            const float* __restrict__ Wr0,
                            u16* __restrict__ xlb, u16* __restrict__ xrb,
                            int* __restrict__ counts, float* __restrict__ muAcc){
    __shared__ float wl[D][FIN+1];
    __shared__ float wr[D][FIN+1];
    __shared__ float xs[32][FIN];
    int tid = threadIdx.x;
    int blk = blockIdx.x;
    int gidx = blk*256 + tid;
    if (gidx < T_NODES) counts[gidx] = 0;             // fused zero
    if (gidx < BGR*D)   muAcc[gidx] = 0.f;
    int rowBase = (blk & 7)*4096 + (blk >> 3)*32;     // XCD swizzle
    for (int i = tid; i < D*FIN; i += 256){
        wl[i>>3][i&7] = Wl0[i];
        wr[i>>3][i&7] = Wr0[i];
    }
    xs[tid>>3][tid&7] = x[rowBase*FIN + tid];
    __syncthreads();
    int wave = tid >> 6, lane = tid & 63;
    int rb = rowBase + wave*8;
    #pragma unroll
    for (int r = 0; r < 8; r++){
        float al = 0.f, ar = 0.f;
        int lr = wave*8 + r;
        #pragma unroll
        for (int k = 0; k < FIN; k++){
            float xv = xs[lr][k];
            al = fmaf(xv, wl[lane][k], al);
            ar = fmaf(xv, wr[lane][k], ar);
        }
        xlb[(size_t)(rb+r)*D + lane] = f2bf(al);
        xrb[(size_t)(rb+r)*D + lane] = f2bf(ar);
    }
}

// ---------------- fused edge+lin, 32 nodes/block (R11 best config) ----------
// LDS: hs fp32 (8.7 KB) + bf16 weights (2 x 8.7 KB) = 26 KB; grid 1024 = 4 blk/CU.
__global__ __launch_bounds__(256) void el_kernel(
        const u16* __restrict__ xlin, const u16* __restrict__ xrin,
        const float* __restrict__ att, const float* __restrict__ bias,
        const int* __restrict__ indptr, const int* __restrict__ col,
        const float* __restrict__ Wl, const float* __restrict__ Wr,
        u16* __restrict__ xlout, u16* __restrict__ xrout, int E){
    __shared__ __align__(16) float hs[32][68];
    __shared__ __align__(16) u16 wls[D][68];
    __shared__ __align__(16) u16 wrs[D][68];
    int tid = threadIdx.x, blk = blockIdx.x;
    int rowBase = (blk & 7)*4096 + (blk >> 3)*32;     // XCD swizzle
    for (int i = tid; i < D*D; i += 256){             // stage weights (bf16 in LDS)
        wls[i>>6][i&63] = f2bf(Wl[i]);
        wrs[i>>6][i&63] = f2bf(Wr[i]);
    }
    int wave = tid >> 6, lane = tid & 63;
    int row = lane >> 4, sub4 = (lane & 15) << 2;
    float4 a4 = *(const float4*)&att[sub4];
    float4 b4 = *(const float4*)&bias[sub4];
    for (int n = 0; n < 8; n++){                      // 8 nodes per wave
        int ln = wave*8 + n;
        int t  = rowBase + ln;
        float4 xr4 = bf4(*(const ushort4*)&xrin[((size_t)t << 6) + sub4]);
        int beg = indptr[t], end = indptr[t+1];
        int deg = end - beg;
        int idx = beg + lane; idx = idx < E ? idx : E - 1;
        int sAll = (lane < deg) ? col[idx] : t;
        int nEdge = deg + 1;
        float4 acc = make_float4(0.f,0.f,0.f,0.f);
        float l = 0.f;
        if      (nEdge <= 16) edge_fast<4>(xlin, sAll, nEdge, row, sub4, a4, xr4, acc, l);
        else if (nEdge <= 24) edge_fast<6>(xlin, sAll, nEdge, row, sub4, a4, xr4, acc, l);
        else if (nEdge <= 32) edge_fast<8>(xlin, sAll, nEdge, row, sub4, a4, xr4, acc, l);
        else edge_slow(xlin, col, beg, deg, t, sAll, nEdge, row, sub4, a4, xr4, acc, l);
        #pragma unroll
        for (int o = 16; o < 64; o <<= 1){
            acc.x += __shfl_xor(acc.x, o, 64);
            acc.y += __shfl_xor(acc.y, o, 64);
            acc.z += __shfl_xor(acc.z, o, 64);
            acc.w += __shfl_xor(acc.w, o, 64);
            l     += __shfl_xor(l,     o, 64);
        }
        if (row == 0){
            float4 hv;
            hv.x = fmaxf(acc.x / l + b4.x, 0.f);      // relu (input to lin)
            hv.y = fmaxf(acc.y / l + b4.y, 0.f);
            hv.z = fmaxf(acc.z / l + b4.z, 0.f);
            hv.w = fmaxf(acc.w / l + b4.w, 0.f);
            *(float4*)&hs[ln][sub4] = hv;
        }
    }
    __syncthreads();
    // ---- lin phase: 32x64 tile, each thread 2 rows x 4 cols x {Wl,Wr} ----
    int ty = tid >> 4, tx = tid & 15;
    int r0 = ty * 2;
    float accl[2][4], accr[2][4];
    #pragma unroll
    for (int i = 0; i < 2; i++)
        #pragma unroll
        for (int j = 0; j < 4; j++){ accl[i][j] = 0.f; accr[i][j] = 0.f; }
    for (int k = 0; k < D; k += 4){
        float4 hv[2], wlv[4], wrv[4];
        #pragma unroll
        for (int i = 0; i < 2; i++)
            hv[i] = *(const float4*)&hs[r0+i][k];
        #pragma unroll
        for (int j = 0; j < 4; j++){
            wlv[j] = bf4(*(const ushort4*)&wls[tx + 16*j][k]);
            wrv[j] = bf4(*(const ushort4*)&wrs[tx + 16*j][k]);
        }
        #pragma unroll
        for (int i = 0; i < 2; i++){
            #pragma unroll
            for (int j = 0; j < 4; j++){
                accl[i][j] += hv[i].x*wlv[j].x + hv[i].y*wlv[j].y
                            + hv[i].z*wlv[j].z + hv[i].w*wlv[j].w;
                accr[i][j] += hv[i].x*wrv[j].x + hv[i].y*wrv[j].y
                            + hv[i].z*wrv[j].z + hv[i].w*wrv[j].w;
            }
        }
    }
    #pragma unroll
    for (int i = 0; i < 2; i++){
        size_t rowOff = (size_t)(rowBase + r0 + i) * D;
        #pragma unroll
        for (int j = 0; j < 4; j++){
            xlout[rowOff + tx + 16*j] = f2bf(accl[i][j]);
            xrout[rowOff + tx + 16*j] = f2bf(accr[i][j]);
        }
    }
}

// ---------------- last edge layer: bf16 in, fp32 h out + graph-mean ----------------
__global__ __launch_bounds__(256) void e4_kernel(
        const u16* __restrict__ xlin, const u16* __restrict__ xrin,
        const float* __restrict__ att, const float* __restrict__ bias,
        const int* __restrict__ indptr, const int* __restrict__ col,
        float* __restrict__ hout, float* __restrict__ muAcc, int E){
    int wave = threadIdx.x >> 6, lane = threadIdx.x & 63;
    int blk = blockIdx.x;
    int t = (blk & 7)*4096 + (blk >> 3)*4 + wave;
    int row = lane >> 4, sub4 = (lane & 15) << 2;
    float4 a4 = *(const float4*)&att[sub4];
    float4 xr4 = bf4(*(const ushort4*)&xrin[((size_t)t << 6) + sub4]);
    int beg = indptr[t], end = indptr[t+1];
    int deg = end - beg;
    int idx = beg + lane; idx = idx < E ? idx : E - 1;
    int sAll = (lane < deg) ? col[idx] : t;
    int nEdge = deg + 1;
    float4 acc = make_float4(0.f,0.f,0.f,0.f);
    float l = 0.f;
    if      (nEdge <= 16) edge_fast<4>(xlin, sAll, nEdge, row, sub4, a4, xr4, acc, l);
    else if (nEdge <= 24) edge_fast<6>(xlin, sAll, nEdge, row, sub4, a4, xr4, acc, l);
    else if (nEdge <= 32) edge_fast<8>(xlin, sAll, nEdge, row, sub4, a4, xr4, acc, l);
    else edge_slow(xlin, col, beg, deg, t, sAll, nEdge, row, sub4, a4, xr4, acc, l);
    #pragma unroll
    for (int o = 16; o < 64; o <<= 1){
        acc.x += __shfl_xor(acc.x, o, 64);
        acc.y += __shfl_xor(acc.y, o, 64);
        acc.z += __shfl_xor(acc.z, o, 64);
        acc.w += __shfl_xor(acc.w, o, 64);
        l     += __shfl_xor(l,     o, 64);
    }
    float4 b4 = *(const float4*)&bias[sub4];
    float4 hv;
    hv.x = acc.x / l + b4.x;                          // NO relu (final h)
    hv.y = acc.y / l + b4.y;
    hv.z = acc.z / l + b4.z;
    hv.w = acc.w / l + b4.w;
    if (row == 0)
        *(float4*)&hout[(size_t)t*D + sub4] = hv;
    __shared__ float red[4][D];
    if (row == 0) *(float4*)&red[wave][sub4] = hv;
    __syncthreads();
    if (wave == 0){
        float s = red[0][lane] + red[1][lane] + red[2][lane] + red[3][lane];
        atomicAdd(&muAcc[(t >> 10)*D + lane], s);
    }
}

// ---------------- per-node head with inlined per-graph pool ----------------
__global__ __launch_bounds__(256) void final_kernel(const float* __restrict__ h,
                             const float* __restrict__ muAcc,
                             const float* __restrict__ t6w, const float* __restrict__ t6b,
                             const float* __restrict__ t7w, const float* __restrict__ t7b,
                             const float* __restrict__ t5pw, const float* __restrict__ t5pb,
                             const float* __restrict__ t5vw, const float* __restrict__ t5vb,
                             const float* __restrict__ pw, const float* __restrict__ pb,
                             const int* __restrict__ reachable,
                             float* __restrict__ out_logits, float* __restrict__ qbuf){
    __shared__ __align__(16) float hs[D][68];
    __shared__ __align__(16) float ws[D][68];
    __shared__ float ppar[D][17];
    __shared__ float qpar[D][17];
    __shared__ float PgQg[2];
    int tid = threadIdx.x;
    int blk = blockIdx.x;
    int rowBase = (blk & 7)*4096 + (blk >> 3)*64;
    int b = rowBase >> 10;
    for (int i = tid; i < D*D; i += 256) ws[i>>6][i&63] = t6w[i];
    if (tid < D) hs[0][tid] = muAcc[b*D + tid] * (1.f/NPG);
    __syncthreads();
    if (tid < D){
        int d = tid;
        float g = t6b[d];
        #pragma unroll
        for (int k = 0; k < D; k++) g = fmaf(hs[0][k], ws[d][k], g);
        g = fmaxf(g, 0.f);
        float pp = wave_sum_bcast(g * t5pw[d]);
        float qq = wave_sum_bcast(g * t5vw[d]);
        if (d == 0){ PgQg[0] = pp; PgQg[1] = qq; }
    }
    __syncthreads();
    for (int i = tid; i < D*D; i += 256){
        int r = i >> 6, c = i & 63;
        hs[r][c] = h[(size_t)rowBase*D + i];
        ws[r][c] = t7w[i];
    }
    __syncthreads();
    int ty = tid >> 4, tx = tid & 15;
    int r0 = ty * 4;
    float acc[4][4];
    #pragma unroll
    for (int i = 0; i < 4; i++)
        #pragma unroll
        for (int j = 0; j < 4; j++) acc[i][j] = 0.f;
    for (int k = 0; k < D; k += 4){
        float4 hv[4], wv[4];
        #pragma unroll
        for (int i = 0; i < 4; i++){
            hv[i] = *(const float4*)&hs[r0+i][k];
            wv[i] = *(const float4*)&ws[tx + 16*i][k];
        }
        #pragma unroll
        for (int i = 0; i < 4; i++)
            #pragma unroll
            for (int j = 0; j < 4; j++)
                acc[i][j] += hv[i].x*wv[j].x + hv[i].y*wv[j].y
                           + hv[i].z*wv[j].z + hv[i].w*wv[j].w;
    }
    float bc[4], pwc[4], qwc[4];
    #pragma unroll
    for (int j = 0; j < 4; j++){
        int c = tx + 16*j;
        bc[j]  = t7b[c];
        pwc[j] = t5pw[D + c];
        qwc[j] = t5vw[D + c];
    }
    #pragma unroll
    for (int i = 0; i < 4; i++){
        float sp = 0.f, sq = 0.f;
        #pragma unroll
        for (int j = 0; j < 4; j++){
            float lv = fmaxf(acc[i][j] + bc[j], 0.f);
            sp = fmaf(lv, pwc[j], sp);
            sq = fmaf(lv, qwc[j], sq);
        }
        ppar[r0+i][tx] = sp;
        qpar[r0+i][tx] = sq;
    }
    __syncthreads();
    if (tid < 64){
        int t = rowBase + tid;
        float sp = 0.f, sq = 0.f;
        #pragma unroll
        for (int c = 0; c < 16; c++){ sp += ppar[tid][c]; sq += qpar[tid][c]; }
        float prob = PgQg[0] + sp + t5pb[0];
        out_logits[t] = prob * pw[0] + pb[0];
        float q = PgQg[1] + sq + t5vb[0];
        if (!reachable[t]) q = -1e20f;
        qbuf[t] = q;
    }
}

// ---------------- per-graph masked max -> value ----------------
__global__ void value_kernel(const float* __restrict__ qbuf, const float* __restrict__ vw,
                             const float* __restrict__ vb, float* __restrict__ out_value){
    __shared__ float part[256];
    int b = blockIdx.x, tid = threadIdx.x;
    float m = -INFINITY;
    for (int i = tid; i < NPG; i += 256) m = fmaxf(m, qbuf[b*NPG + i]);
    part[tid] = m;
    __syncthreads();
    for (int s = 128; s > 0; s >>= 1){
        if (tid < s) part[tid] = fmaxf(part[tid], part[tid+s]);
        __syncthreads();
    }
    if (tid == 0) out_value[b] = part[0]*vw[0] + vb[0];
}

extern "C" void kernel_launch(void* const* d_in, const int* in_sizes, int n_in,
                              void* d_out, int out_size, void* d_ws, size_t ws_size,
                              hipStream_t stream){
    const float* x          = (const float*)d_in[0];
    const int*   edge_index = (const int*)d_in[1];
    const int*   reachable  = (const int*)d_in[2];
    const float* Wl0 = (const float*)d_in[3];
    const float* Wr0 = (const float*)d_in[4];
    const float* att0= (const float*)d_in[5];
    const float* b0  = (const float*)d_in[6];
    const float* Wl  = (const float*)d_in[7];
    const float* Wr  = (const float*)d_in[8];
    const float* att = (const float*)d_in[9];
    const float* bb  = (const float*)d_in[10];
    const float* t6w = (const float*)d_in[11];
    const float* t6b = (const float*)d_in[12];
    const float* t7w = (const float*)d_in[13];
    const float* t7b = (const float*)d_in[14];
    const float* t5pw= (const float*)d_in[15];
    const float* t5pb= (const float*)d_in[16];
    const float* t5vw= (const float*)d_in[17];
    const float* t5vb= (const float*)d_in[18];
    const float* pw  = (const float*)d_in[19];
    const float* pb  = (const float*)d_in[20];
    const float* vw  = (const float*)d_in[21];
    const float* vb  = (const float*)d_in[22];

    int E = in_sizes[1] / 2;
    const int* esrc = edge_index;
    const int* edst = edge_index + E;

    char* ws = (char*)d_ws;
    float* h    = (float*)(ws);
    u16* xlbA   = (u16*)(ws + (size_t)T_NODES*D*4);
    u16* xrbA   = (u16*)((char*)xlbA + (size_t)T_NODES*D*2);
    u16* xlbB   = (u16*)((char*)xrbA + (size_t)T_NODES*D*2);
    u16* xrbB   = (u16*)((char*)xlbB + (size_t)T_NODES*D*2);
    int* counts = (int*)((char*)xrbB + (size_t)T_NODES*D*2);
    int* indptr = (int*)((char*)counts + (size_t)(T_NODES+16)*4);
    int* cursor = (int*)((char*)indptr + (size_t)(T_NODES+16)*4);
    int* col    = (int*)((char*)cursor + (size_t)(T_NODES+16)*4);
    float* qbuf = (float*)((char*)col + (size_t)(E+64)*4);
    float* muAcc= (float*)((char*)qbuf + (size_t)T_NODES*4);

    lin0_kernel<<<T_NODES/32, 256, 0, stream>>>(x, Wl0, Wr0, xlbA, xrbA, counts, muAcc);
    count_kernel<<<(E+255)/256, 256, 0, stream>>>(edst, counts, E);
    scan_kernel<<<1, 1024, 0, stream>>>(counts, indptr, cursor, T_NODES);
    scatter_kernel<<<(E+255)/256, 256, 0, stream>>>(esrc, edst, cursor, col, E);

    // EL_i: edge of layer i (+relu) then lin with Wl[i]/Wr[i]; ping-pong A/B
    el_kernel<<<T_NODES/32, 256, 0, stream>>>(xlbA, xrbA, att0, b0, indptr, col,
                                              Wl + 0*D*D, Wr + 0*D*D, xlbB, xrbB, E);
    el_kernel<<<T_NODES/32, 256, 0, stream>>>(xlbB, xrbB, att + 0*D, bb + 0*D, indptr, col,
                                              Wl + 1*D*D, Wr + 1*D*D, xlbA, xrbA, E);
    el_kernel<<<T_NODES/32, 256, 0, stream>>>(xlbA, xrbA, att + 1*D, bb + 1*D, indptr, col,
                                              Wl + 2*D*D, Wr + 2*D*D, xlbB, xrbB, E);
    el_kernel<<<T_NODES/32, 256, 0, stream>>>(xlbB, xrbB, att + 2*D, bb + 2*D, indptr, col,
                                              Wl + 3*D*D, Wr + 3*D*D, xlbA, xrbA, E);
    e4_kernel<<<T_NODES/4, 256, 0, stream>>>(xlbA, xrbA, att + 3*D, bb + 3*D, indptr, col,
                                             h, muAcc, E);

    final_kernel<<<T_NODES/64, 256, 0, stream>>>(h, muAcc, t6w, t6b, t7w, t7b,
                                                 t5pw, t5pb, t5vw, t5vb, pw, pb,
                                                 reachable, (float*)d_out, qbuf);
    value_kernel<<<BGR, 256, 0, stream>>>(qbuf, vw, vb, (float*)d_out + T_NODES);
}